// Round 1
// baseline (43.276 us; speedup 1.0000x reference)
//
#include <hip/hip_runtime.h>

// CenterNet 3x3 NMS: out = (p == max3x3(p, zero-padded)) ? p : 0
// Input: [16, 80, 128, 128] fp32. Plane = 128x128 = 16384 floats = 4096 float4.
// One thread handles 4 contiguous pixels (one float4).

#define PLANE_F4   4096   // float4 per 128x128 plane
#define ROW_F4     32     // float4 per row
#define PLANE_F    16384
#define ROW_F      128

__global__ __launch_bounds__(256) void centernet_nms_kernel(
    const float* __restrict__ in, float* __restrict__ out, int total_f4)
{
    int i4 = blockIdx.x * blockDim.x + threadIdx.x;
    if (i4 >= total_f4) return;

    const int plane = i4 >> 12;          // / PLANE_F4
    const int within = i4 & (PLANE_F4 - 1);
    const int row = within >> 5;         // / ROW_F4
    const int col4 = within & (ROW_F4 - 1);
    const int w0 = col4 << 2;

    const float* pbase = in + (long)plane * PLANE_F;
    const float4* pbase4 = reinterpret_cast<const float4*>(pbase);

    float4 rowmax[3];
    float4 center;

    #pragma unroll
    for (int dr = -1; dr <= 1; ++dr) {
        const int r = row + dr;
        float4 v = make_float4(0.f, 0.f, 0.f, 0.f);
        float l = 0.f, rt = 0.f;
        if (r >= 0 && r < ROW_F) {
            v = pbase4[r * ROW_F4 + col4];
            if (col4 > 0)          l  = pbase[r * ROW_F + w0 - 1];
            if (col4 < ROW_F4 - 1) rt = pbase[r * ROW_F + w0 + 4];
        }
        float4 m;
        m.x = fmaxf(fmaxf(l,   v.x), v.y);
        m.y = fmaxf(fmaxf(v.x, v.y), v.z);
        m.z = fmaxf(fmaxf(v.y, v.z), v.w);
        m.w = fmaxf(fmaxf(v.z, v.w), rt);
        rowmax[dr + 1] = m;
        if (dr == 0) center = v;
    }

    float4 m;
    m.x = fmaxf(fmaxf(rowmax[0].x, rowmax[1].x), rowmax[2].x);
    m.y = fmaxf(fmaxf(rowmax[0].y, rowmax[1].y), rowmax[2].y);
    m.z = fmaxf(fmaxf(rowmax[0].z, rowmax[1].z), rowmax[2].z);
    m.w = fmaxf(fmaxf(rowmax[0].w, rowmax[1].w), rowmax[2].w);

    float4 o;
    o.x = (center.x == m.x) ? center.x : 0.f;
    o.y = (center.y == m.y) ? center.y : 0.f;
    o.z = (center.z == m.z) ? center.z : 0.f;
    o.w = (center.w == m.w) ? center.w : 0.f;

    reinterpret_cast<float4*>(out)[i4] = o;
}

extern "C" void kernel_launch(void* const* d_in, const int* in_sizes, int n_in,
                              void* d_out, int out_size, void* d_ws, size_t ws_size,
                              hipStream_t stream) {
    const float* in = (const float*)d_in[0];
    float* out = (float*)d_out;
    const int total_f4 = out_size / 4;          // 5,242,880
    const int block = 256;
    const int grid = (total_f4 + block - 1) / block;  // 20480
    centernet_nms_kernel<<<grid, block, 0, stream>>>(in, out, total_f4);
}

// Round 2
// 29.687 us; speedup vs baseline: 1.4577x; 1.4577x over previous
//
#include <hip/hip_runtime.h>

// CenterNet 3x3 NMS: out = (p == max3x3(p, zero-padded)) ? p : 0
// Input: [16, 80, 128, 128] fp32.
// Thread = one float4-column x 8 consecutive rows. Horizontal halo via shuffles.

#define ROW_F4   32     // float4 per row
#define PLANE_F4 4096   // float4 per 128x128 plane
#define ROWS     128
#define RPT      8      // rows per thread

__global__ __launch_bounds__(256) void centernet_nms_kernel(
    const float4* __restrict__ in, float4* __restrict__ out, int total_threads)
{
    const int t = blockIdx.x * blockDim.x + threadIdx.x;
    if (t >= total_threads) return;

    const int col4   = t & 31;          // lane&31 == col4: lane+/-1 is horizontal neighbor
    const int rowgrp = (t >> 5) & 15;   // 128/RPT = 16 row groups
    const int plane  = t >> 9;
    const int r0     = rowgrp * RPT;

    const float4* p4 = in + (long)plane * PLANE_F4 + col4;

    // Load RPT+2 rows (with vertical zero halo). All loads independent.
    float4 v[RPT + 2];
    #pragma unroll
    for (int k = 0; k < RPT + 2; ++k) {
        const int r = r0 - 1 + k;
        if (r >= 0 && r < ROWS)
            v[k] = p4[r * ROW_F4];
        else
            v[k] = make_float4(0.f, 0.f, 0.f, 0.f);
    }

    // Horizontal 3-max per loaded row; halo from neighbor lanes.
    float4 h[RPT + 2];
    #pragma unroll
    for (int k = 0; k < RPT + 2; ++k) {
        float l  = __shfl_up(v[k].w, 1);   // lane-1's last element
        float rt = __shfl_down(v[k].x, 1); // lane+1's first element
        if (col4 == 0)          l  = 0.f;  // row-edge zero padding
        if (col4 == ROW_F4 - 1) rt = 0.f;
        h[k].x = fmaxf(fmaxf(l,      v[k].x), v[k].y);
        h[k].y = fmaxf(fmaxf(v[k].x, v[k].y), v[k].z);
        h[k].z = fmaxf(fmaxf(v[k].y, v[k].z), v[k].w);
        h[k].w = fmaxf(fmaxf(v[k].z, v[k].w), rt);
    }

    // Vertical 3-max + compare-select, RPT output rows.
    float4* o4 = out + (long)plane * PLANE_F4 + col4;
    #pragma unroll
    for (int j = 0; j < RPT; ++j) {
        float4 m;
        m.x = fmaxf(fmaxf(h[j].x, h[j + 1].x), h[j + 2].x);
        m.y = fmaxf(fmaxf(h[j].y, h[j + 1].y), h[j + 2].y);
        m.z = fmaxf(fmaxf(h[j].z, h[j + 1].z), h[j + 2].z);
        m.w = fmaxf(fmaxf(h[j].w, h[j + 1].w), h[j + 2].w);
        const float4 c = v[j + 1];
        float4 o;
        o.x = (c.x == m.x) ? c.x : 0.f;
        o.y = (c.y == m.y) ? c.y : 0.f;
        o.z = (c.z == m.z) ? c.z : 0.f;
        o.w = (c.w == m.w) ? c.w : 0.f;
        o4[(r0 + j) * ROW_F4] = o;
    }
}

extern "C" void kernel_launch(void* const* d_in, const int* in_sizes, int n_in,
                              void* d_out, int out_size, void* d_ws, size_t ws_size,
                              hipStream_t stream) {
    const float4* in = (const float4*)d_in[0];
    float4* out = (float4*)d_out;
    const int planes = out_size / (PLANE_F4 * 4);          // 1280
    const int total_threads = planes * ROW_F4 * (ROWS / RPT);  // 655,360
    const int block = 256;
    const int grid = (total_threads + block - 1) / block;  // 2560
    centernet_nms_kernel<<<grid, block, 0, stream>>>(in, out, total_threads);
}

// Round 3
// 29.430 us; speedup vs baseline: 1.4705x; 1.0087x over previous
//
#include <hip/hip_runtime.h>

// CenterNet 3x3 NMS: out = (p == max3x3(p, zero-padded)) ? p : 0
// Input: [16, 80, 128, 128] fp32.
// Thread = one float4-column x 8 consecutive rows. Horizontal halo via shuffles.
// Output stored non-temporally (never re-read) to keep input L3-resident.

#define ROW_F4   32     // float4 per row
#define PLANE_F4 4096   // float4 per 128x128 plane
#define ROWS     128
#define RPT      8      // rows per thread

typedef float f32x4 __attribute__((ext_vector_type(4)));

__global__ __launch_bounds__(256) void centernet_nms_kernel(
    const float4* __restrict__ in, f32x4* __restrict__ out, int total_threads)
{
    const int t = blockIdx.x * blockDim.x + threadIdx.x;
    if (t >= total_threads) return;

    const int col4   = t & 31;          // lane&31 == col4: lane+/-1 is horizontal neighbor
    const int rowgrp = (t >> 5) & 15;   // 128/RPT = 16 row groups
    const int plane  = t >> 9;
    const int r0     = rowgrp * RPT;

    const float4* p4 = in + (long)plane * PLANE_F4 + col4;

    // Load RPT+2 rows (with vertical zero halo). All loads independent.
    float4 v[RPT + 2];
    #pragma unroll
    for (int k = 0; k < RPT + 2; ++k) {
        const int r = r0 - 1 + k;
        if (r >= 0 && r < ROWS)
            v[k] = p4[r * ROW_F4];
        else
            v[k] = make_float4(0.f, 0.f, 0.f, 0.f);
    }

    // Horizontal 3-max per loaded row; halo from neighbor lanes.
    float4 h[RPT + 2];
    #pragma unroll
    for (int k = 0; k < RPT + 2; ++k) {
        float l  = __shfl_up(v[k].w, 1);   // lane-1's last element
        float rt = __shfl_down(v[k].x, 1); // lane+1's first element
        if (col4 == 0)          l  = 0.f;  // row-edge zero padding
        if (col4 == ROW_F4 - 1) rt = 0.f;
        h[k].x = fmaxf(fmaxf(l,      v[k].x), v[k].y);
        h[k].y = fmaxf(fmaxf(v[k].x, v[k].y), v[k].z);
        h[k].z = fmaxf(fmaxf(v[k].y, v[k].z), v[k].w);
        h[k].w = fmaxf(fmaxf(v[k].z, v[k].w), rt);
    }

    // Vertical 3-max + compare-select, RPT output rows. Non-temporal stores.
    f32x4* o4 = out + (long)plane * PLANE_F4 + col4;
    #pragma unroll
    for (int j = 0; j < RPT; ++j) {
        float4 m;
        m.x = fmaxf(fmaxf(h[j].x, h[j + 1].x), h[j + 2].x);
        m.y = fmaxf(fmaxf(h[j].y, h[j + 1].y), h[j + 2].y);
        m.z = fmaxf(fmaxf(h[j].z, h[j + 1].z), h[j + 2].z);
        m.w = fmaxf(fmaxf(h[j].w, h[j + 1].w), h[j + 2].w);
        const float4 c = v[j + 1];
        f32x4 o;
        o.x = (c.x == m.x) ? c.x : 0.f;
        o.y = (c.y == m.y) ? c.y : 0.f;
        o.z = (c.z == m.z) ? c.z : 0.f;
        o.w = (c.w == m.w) ? c.w : 0.f;
        __builtin_nontemporal_store(o, &o4[(r0 + j) * ROW_F4]);
    }
}

extern "C" void kernel_launch(void* const* d_in, const int* in_sizes, int n_in,
                              void* d_out, int out_size, void* d_ws, size_t ws_size,
                              hipStream_t stream) {
    const float4* in = (const float4*)d_in[0];
    f32x4* out = (f32x4*)d_out;
    const int planes = out_size / (PLANE_F4 * 4);          // 1280
    const int total_threads = planes * ROW_F4 * (ROWS / RPT);  // 655,360
    const int block = 256;
    const int grid = (total_threads + block - 1) / block;  // 2560
    centernet_nms_kernel<<<grid, block, 0, stream>>>(in, out, total_threads);
}